// Round 1
// baseline (608.519 us; speedup 1.0000x reference)
//
#include <hip/hip_runtime.h>
#include <hip/hip_bf16.h>

#define DEV static __device__ __forceinline__

typedef __attribute__((ext_vector_type(8))) short short8;
typedef __attribute__((ext_vector_type(4))) short short4v;
typedef __attribute__((ext_vector_type(4))) float float4v;

DEV unsigned short f2bf(float f) {
  unsigned int u = __builtin_bit_cast(unsigned int, f);
  u = (u + 0x7fffu + ((u >> 16) & 1u)) >> 16;
  return (unsigned short)u;
}

DEV __attribute__((address_space(3))) void* to_lds(void* p) {
  return (__attribute__((address_space(3))) void*)p;
}
DEV const __attribute__((address_space(1))) void* to_glb(const void* p) {
  return (const __attribute__((address_space(1))) void*)p;
}

DEV float4v zero4() { float4v z = {0.f, 0.f, 0.f, 0.f}; return z; }

// ---------------------------------------------------------------- convert
__global__ __launch_bounds__(256)
void f32_to_bf16_kn(const float* __restrict__ src, unsigned short* __restrict__ dst, int n) {
  int i = (blockIdx.x * blockDim.x + threadIdx.x) * 4;
  int stride = gridDim.x * blockDim.x * 4;
  for (; i < n; i += stride) {
    float4v v = *reinterpret_cast<const float4v*>(src + i);
    short4v o;
    o[0] = (short)f2bf(v[0]);
    o[1] = (short)f2bf(v[1]);
    o[2] = (short)f2bf(v[2]);
    o[3] = (short)f2bf(v[3]);
    *reinterpret_cast<short4v*>(dst + i) = o;
  }
}

// ---------------------------------------------------------------- GEMM (B^T form)
// C[m,n] = sum_k A[m,k] * B[n,k] + bias[n];  A:[M,K] bf16, B:[N,K] bf16
// BM=BN=128, BK=64, 256 threads (4 waves, 2x2), each wave 64x64 out.
template<int OUT_F32>
__global__ __launch_bounds__(256, 2)
void gemm_bt_kn(const unsigned short* __restrict__ A, const unsigned short* __restrict__ B,
                const float* __restrict__ bias, void* __restrict__ Cout,
                int M, int N, int K) {
  __shared__ unsigned short sA[128 * 64];
  __shared__ unsigned short sB[128 * 64];
  const int t = threadIdx.x;
  const int wave = t >> 6, lane = t & 63;
  const int wm = wave >> 1, wn = wave & 1;
  const int m0 = blockIdx.y * 128, n0 = blockIdx.x * 128;
  const int l15 = lane & 15, l4 = lane >> 4;

  float4v acc[4][4];
#pragma unroll
  for (int i = 0; i < 4; i++)
#pragma unroll
    for (int j = 0; j < 4; j++) acc[i][j] = zero4();

  const int row_s = t >> 3;            // (t*16)/128
  const int cols_s = (t & 7) * 8;      // shorts

  for (int k0 = 0; k0 < K; k0 += 64) {
    __syncthreads();
#pragma unroll
    for (int i = 0; i < 4; i++) {
      const unsigned short* ga = &A[(size_t)(m0 + row_s + i * 32) * K + k0 + cols_s];
      __builtin_amdgcn_global_load_lds(to_glb(ga), to_lds(&sA[(i * 4096 + wave * 1024) / 2]), 16, 0, 0);
    }
#pragma unroll
    for (int i = 0; i < 4; i++) {
      const unsigned short* gb = &B[(size_t)(n0 + row_s + i * 32) * K + k0 + cols_s];
      __builtin_amdgcn_global_load_lds(to_glb(gb), to_lds(&sB[(i * 4096 + wave * 1024) / 2]), 16, 0, 0);
    }
    __syncthreads();
#pragma unroll
    for (int kc = 0; kc < 2; kc++) {
      short8 af[4], bf[4];
#pragma unroll
      for (int mf = 0; mf < 4; mf++) {
        int row = wm * 64 + mf * 16 + l15;
        af[mf] = *reinterpret_cast<const short8*>(&sA[row * 64 + kc * 32 + l4 * 8]);
      }
#pragma unroll
      for (int nf = 0; nf < 4; nf++) {
        int row = wn * 64 + nf * 16 + l15;
        bf[nf] = *reinterpret_cast<const short8*>(&sB[row * 64 + kc * 32 + l4 * 8]);
      }
#pragma unroll
      for (int mf = 0; mf < 4; mf++)
#pragma unroll
        for (int nf = 0; nf < 4; nf++)
          acc[mf][nf] = __builtin_amdgcn_mfma_f32_16x16x32_bf16(af[mf], bf[nf], acc[mf][nf], 0, 0, 0);
    }
  }

#pragma unroll
  for (int mf = 0; mf < 4; mf++) {
#pragma unroll
    for (int nf = 0; nf < 4; nf++) {
#pragma unroll
      for (int r = 0; r < 4; r++) {
        int row = m0 + wm * 64 + mf * 16 + l4 * 4 + r;
        int col = n0 + wn * 64 + nf * 16 + l15;
        float v = acc[mf][nf][r] + bias[col];
        if (OUT_F32)
          ((float*)Cout)[(size_t)row * N + col] = v;
        else
          ((unsigned short*)Cout)[(size_t)row * N + col] = f2bf(v);
      }
    }
  }
}

// ---------------------------------------------------------------- attention
// qkv: [B*T, 3072] bf16 (q|k|v each 1024). y: [B*T, 1024] bf16.
// grid: (T/64, B*H). 4 waves/block; wave handles 16 q rows; KVBLK=32.
__global__ __launch_bounds__(256, 2)
void attn_kn(const unsigned short* __restrict__ qkv, unsigned short* __restrict__ y) {
  __shared__ unsigned short ldsP[4][16][32];
  const int t = threadIdx.x;
  const int wave = t >> 6, lane = t & 63;
  const int l15 = lane & 15, l4 = lane >> 4;
  const int qt = blockIdx.x;
  const int bh = blockIdx.y;
  const int b = bh >> 4, h = bh & 15;
  const int q0 = qt * 64 + wave * 16;
  const int T = 2048;

  const size_t base = (size_t)b * T * 3072;
  const unsigned short* Q = qkv + base + (size_t)h * 64;
  const unsigned short* Kp = qkv + base + 1024 + (size_t)h * 64;
  const unsigned short* Vp = qkv + base + 2048 + (size_t)h * 64;

  short8 qf[2];
#pragma unroll
  for (int kc = 0; kc < 2; kc++)
    qf[kc] = *reinterpret_cast<const short8*>(&Q[(size_t)(q0 + l15) * 3072 + kc * 32 + l4 * 8]);

  float4v o_acc[4];
#pragma unroll
  for (int f = 0; f < 4; f++) o_acc[f] = zero4();
  float m_r[4], l_r[4];
#pragma unroll
  for (int r = 0; r < 4; r++) { m_r[r] = -1e30f; l_r[r] = 0.f; }

  const float scale = 0.125f;  // 1/sqrt(64)

  for (int kv0 = 0; kv0 <= q0 + 15; kv0 += 32) {
    // S = Q K^T  (rows q, cols kv)
    float4v s[2];
#pragma unroll
    for (int c = 0; c < 2; c++) {
      s[c] = zero4();
#pragma unroll
      for (int kc = 0; kc < 2; kc++) {
        int kr = kv0 + c * 16 + l15;
        kr = kr < T - 1 ? kr : T - 1;
        short8 kf = *reinterpret_cast<const short8*>(&Kp[(size_t)kr * 3072 + kc * 32 + l4 * 8]);
        s[c] = __builtin_amdgcn_mfma_f32_16x16x32_bf16(qf[kc], kf, s[c], 0, 0, 0);
      }
    }
    // mask + scale + row max
    float pmax[4];
#pragma unroll
    for (int r = 0; r < 4; r++) {
      int qrow = q0 + l4 * 4 + r;
#pragma unroll
      for (int c = 0; c < 2; c++) {
        int kvi = kv0 + c * 16 + l15;
        float v = s[c][r] * scale;
        s[c][r] = (kvi <= qrow) ? v : -1e30f;
      }
      pmax[r] = fmaxf(s[0][r], s[1][r]);
    }
#pragma unroll
    for (int msk = 1; msk < 16; msk <<= 1)
#pragma unroll
      for (int r = 0; r < 4; r++) pmax[r] = fmaxf(pmax[r], __shfl_xor(pmax[r], msk, 64));

    float psum[4];
#pragma unroll
    for (int r = 0; r < 4; r++) {
      float newm = fmaxf(m_r[r], pmax[r]);
      float sc = __expf(m_r[r] - newm);
      m_r[r] = newm;
      l_r[r] *= sc;
#pragma unroll
      for (int f = 0; f < 4; f++) o_acc[f][r] *= sc;
      float p0 = __expf(s[0][r] - newm);
      float p1 = __expf(s[1][r] - newm);
      s[0][r] = p0;
      s[1][r] = p1;
      psum[r] = p0 + p1;
    }
#pragma unroll
    for (int msk = 1; msk < 16; msk <<= 1)
#pragma unroll
      for (int r = 0; r < 4; r++) psum[r] += __shfl_xor(psum[r], msk, 64);
#pragma unroll
    for (int r = 0; r < 4; r++) l_r[r] += psum[r];

    // P -> LDS (bf16), then read back in A-frag layout
#pragma unroll
    for (int c = 0; c < 2; c++)
#pragma unroll
      for (int r = 0; r < 4; r++)
        ldsP[wave][l4 * 4 + r][c * 16 + l15] = f2bf(s[c][r]);
    asm volatile("s_waitcnt lgkmcnt(0)" ::: "memory");
    short8 pf = *reinterpret_cast<const short8*>(&ldsP[wave][l15][l4 * 8]);

    // PV
#pragma unroll
    for (int f = 0; f < 4; f++) {
      short8 vf;
#pragma unroll
      for (int j = 0; j < 8; j++) {
        int vr = kv0 + l4 * 8 + j;
        vr = vr < T - 1 ? vr : T - 1;
        vf[j] = (short)Vp[(size_t)vr * 3072 + f * 16 + l15];
      }
      o_acc[f] = __builtin_amdgcn_mfma_f32_16x16x32_bf16(pf, vf, o_acc[f], 0, 0, 0);
    }
  }

  unsigned short* yrow = y + (size_t)b * T * 1024 + h * 64;
#pragma unroll
  for (int f = 0; f < 4; f++) {
#pragma unroll
    for (int r = 0; r < 4; r++) {
      int q = q0 + l4 * 4 + r;
      float v = o_acc[f][r] / l_r[r];
      yrow[(size_t)q * 1024 + f * 16 + l15] = f2bf(v);
    }
  }
}

// ---------------------------------------------------------------- launch
extern "C" void kernel_launch(void* const* d_in, const int* in_sizes, int n_in,
                              void* d_out, int out_size, void* d_ws, size_t ws_size,
                              hipStream_t stream) {
  const float* x = (const float*)d_in[0];       // [4,2048,1024]
  const float* w_qkv = (const float*)d_in[1];   // [3072,1024]
  const float* b_qkv = (const float*)d_in[2];   // [3072]
  const float* w_proj = (const float*)d_in[3];  // [1024,1024]
  const float* b_proj = (const float*)d_in[4];  // [1024]
  float* out = (float*)d_out;                   // [4,2048,1024] f32
  char* ws = (char*)d_ws;

  const int M = 4 * 2048;  // 8192 rows
  unsigned short* x_bf = (unsigned short*)ws;                        // 16 MB
  unsigned short* wqkv_bf = (unsigned short*)(ws + (22ull << 20));   // 6 MB
  unsigned short* wproj_bf = (unsigned short*)(ws + (28ull << 20));  // 2 MB
  unsigned short* qkv = (unsigned short*)(ws + (30ull << 20));       // 48 MB
  unsigned short* y_bf = x_bf;  // reuse x region after QKV GEMM

  f32_to_bf16_kn<<<2048, 256, 0, stream>>>(x, x_bf, M * 1024);
  f32_to_bf16_kn<<<1024, 256, 0, stream>>>(w_qkv, wqkv_bf, 3072 * 1024);
  f32_to_bf16_kn<<<512, 256, 0, stream>>>(w_proj, wproj_bf, 1024 * 1024);

  gemm_bt_kn<0><<<dim3(3072 / 128, M / 128), 256, 0, stream>>>(x_bf, wqkv_bf, b_qkv, qkv, M, 3072, 1024);

  attn_kn<<<dim3(2048 / 64, 64), 256, 0, stream>>>(qkv, y_bf);

  gemm_bt_kn<1><<<dim3(1024 / 128, M / 128), 256, 0, stream>>>(y_bf, wproj_bf, b_proj, out, M, 1024, 1024);
}

// Round 2
// 252.145 us; speedup vs baseline: 2.4134x; 2.4134x over previous
//
#include <hip/hip_runtime.h>
#include <hip/hip_bf16.h>

#define DEV static __device__ __forceinline__

typedef __attribute__((ext_vector_type(8))) short short8;
typedef __attribute__((ext_vector_type(4))) short short4v;
typedef __attribute__((ext_vector_type(4))) float float4v;
typedef __attribute__((ext_vector_type(4))) int int4v;

DEV unsigned short f2bf(float f) {
  unsigned int u = __builtin_bit_cast(unsigned int, f);
  u = (u + 0x7fffu + ((u >> 16) & 1u)) >> 16;
  return (unsigned short)u;
}

DEV __attribute__((address_space(3))) void* to_lds(void* p) {
  return (__attribute__((address_space(3))) void*)p;
}
DEV const __attribute__((address_space(1))) void* to_glb(const void* p) {
  return (const __attribute__((address_space(1))) void*)p;
}

DEV float4v zero4() { float4v z = {0.f, 0.f, 0.f, 0.f}; return z; }

DEV float ex2(float x) {  // hardware exp2
  float r;
  asm("v_exp_f32 %0, %1" : "=v"(r) : "v"(x));
  return r;
}
DEV unsigned int cvtpk(float lo, float hi) {  // packed bf16 {lo, hi}
  unsigned int r;
  asm("v_cvt_pk_bf16_f32 %0, %1, %2" : "=v"(r) : "v"(lo), "v"(hi));
  return r;
}

// ---------------------------------------------------------------- convert
__global__ __launch_bounds__(256)
void f32_to_bf16_kn(const float* __restrict__ src, unsigned short* __restrict__ dst, int n) {
  int i = (blockIdx.x * blockDim.x + threadIdx.x) * 4;
  int stride = gridDim.x * blockDim.x * 4;
  for (; i < n; i += stride) {
    float4v v = *reinterpret_cast<const float4v*>(src + i);
    short4v o;
    o[0] = (short)f2bf(v[0]);
    o[1] = (short)f2bf(v[1]);
    o[2] = (short)f2bf(v[2]);
    o[3] = (short)f2bf(v[3]);
    *reinterpret_cast<short4v*>(dst + i) = o;
  }
}

// ---------------------------------------------------------------- GEMM (B^T form)
// C[m,n] = sum_k A[m,k]*B[n,k] + bias[n]. 128x128 tile, BK=64, 4 waves.
// LDS XOR-swizzled via pre-swizzled global source (rule #21).
template<int OUT_F32>
__global__ __launch_bounds__(256, 2)
void gemm_bt_kn(const unsigned short* __restrict__ A, const unsigned short* __restrict__ B,
                const float* __restrict__ bias, void* __restrict__ Cout,
                int M, int N, int K) {
  __shared__ unsigned short sA[128 * 64];
  __shared__ unsigned short sB[128 * 64];
  const int t = threadIdx.x;
  const int wave = t >> 6, lane = t & 63;
  const int wm = wave >> 1, wn = wave & 1;
  const int m0 = blockIdx.y * 128, n0 = blockIdx.x * 128;
  const int l15 = lane & 15, l4 = lane >> 4;

  float4v acc[4][4];
#pragma unroll
  for (int i = 0; i < 4; i++)
#pragma unroll
    for (int j = 0; j < 4; j++) acc[i][j] = zero4();

  const int row_s = t >> 3;
  const int cols_s = ((t & 7) ^ ((t >> 3) & 7)) * 8;  // pre-swizzled source column

  for (int k0 = 0; k0 < K; k0 += 64) {
    __syncthreads();
#pragma unroll
    for (int i = 0; i < 4; i++) {
      const unsigned short* ga = &A[(size_t)(m0 + row_s + i * 32) * K + k0 + cols_s];
      __builtin_amdgcn_global_load_lds(to_glb(ga), to_lds(&sA[(i * 4096 + wave * 1024) / 2]), 16, 0, 0);
    }
#pragma unroll
    for (int i = 0; i < 4; i++) {
      const unsigned short* gb = &B[(size_t)(n0 + row_s + i * 32) * K + k0 + cols_s];
      __builtin_amdgcn_global_load_lds(to_glb(gb), to_lds(&sB[(i * 4096 + wave * 1024) / 2]), 16, 0, 0);
    }
    __syncthreads();
#pragma unroll
    for (int kc = 0; kc < 2; kc++) {
      short8 af[4], bf[4];
#pragma unroll
      for (int mf = 0; mf < 4; mf++) {
        int off = ((wm * 64 + mf * 16 + l15) * 128 + kc * 64 + l4 * 16) ^ ((l15 & 7) << 4);
        af[mf] = *reinterpret_cast<const short8*>((const char*)sA + off);
      }
#pragma unroll
      for (int nf = 0; nf < 4; nf++) {
        int off = ((wn * 64 + nf * 16 + l15) * 128 + kc * 64 + l4 * 16) ^ ((l15 & 7) << 4);
        bf[nf] = *reinterpret_cast<const short8*>((const char*)sB + off);
      }
#pragma unroll
      for (int mf = 0; mf < 4; mf++)
#pragma unroll
        for (int nf = 0; nf < 4; nf++)
          acc[mf][nf] = __builtin_amdgcn_mfma_f32_16x16x32_bf16(af[mf], bf[nf], acc[mf][nf], 0, 0, 0);
    }
  }

#pragma unroll
  for (int mf = 0; mf < 4; mf++) {
#pragma unroll
    for (int nf = 0; nf < 4; nf++) {
#pragma unroll
      for (int r = 0; r < 4; r++) {
        int row = m0 + wm * 64 + mf * 16 + l4 * 4 + r;
        int col = n0 + wn * 64 + nf * 16 + l15;
        float v = acc[mf][nf][r] + bias[col];
        if (OUT_F32)
          ((float*)Cout)[(size_t)row * N + col] = v;
        else
          ((unsigned short*)Cout)[(size_t)row * N + col] = f2bf(v);
      }
    }
  }
}

// ---------------------------------------------------------------- attention
// Flash-style, swapped QK^T (S^T = K·Q^T), KVBLK=64, 4 waves x 32 q rows.
// K staged via global_load_lds w/ pre-swizzled source; V transposed to V^T in
// LDS during reg-staging; P bounced via packed b64 writes. All LDS reads
// XOR-swizzled.
__global__ __launch_bounds__(256, 2)
void attn_kn(const unsigned short* __restrict__ qkv, unsigned short* __restrict__ y) {
  __shared__ unsigned short sK[2][4096];   // [64 kv][64 d], swizzle key (row&7)<<4
  __shared__ unsigned short sVT[2][4096];  // [64 d][64 kv], swizzle key ((d>>3)&7)<<4
  __shared__ unsigned short sP[4][2048];   // per-wave [32 q][64 kv], key (q&7)<<4
  const int t = threadIdx.x;
  const int wave = t >> 6, lane = t & 63;
  const int l15 = lane & 15, l4 = lane >> 4;
  const int qt = gridDim.x - 1 - blockIdx.x;  // heavy blocks first
  const int bh = blockIdx.y;
  const int b = bh >> 4, h = bh & 15;
  const int T = 2048;
  const int q0w = qt * 128 + wave * 32;
  const int q_end = q0w + 31;
  const size_t base = (size_t)b * T * 3072;
  const unsigned short* Qp = qkv + base + h * 64;
  const unsigned short* Kp = qkv + base + 1024 + h * 64;
  const unsigned short* Vp = qkv + base + 2048 + h * 64;

  // Q b-frags: lane holds Q[q0w + m*16 + l15][kc*32 + l4*8 ..+8]
  short8 qf[2][2];
#pragma unroll
  for (int m = 0; m < 2; m++)
#pragma unroll
    for (int kc = 0; kc < 2; kc++)
      qf[m][kc] = *reinterpret_cast<const short8*>(
          &Qp[(size_t)(q0w + m * 16 + l15) * 3072 + kc * 32 + l4 * 8]);

  float4v o_acc[2][4];
#pragma unroll
  for (int m = 0; m < 2; m++)
#pragma unroll
    for (int f = 0; f < 4; f++) o_acc[m][f] = zero4();
  float m_r[2] = {-1e30f, -1e30f};
  float l_r[2] = {0.f, 0.f};
  const float scl = 0.125f * 1.44269504089f;  // 1/sqrt(64) * log2(e)

  const int vkp = t >> 3;       // k-pair index 0..31
  const int vd0 = (t & 7) * 8;  // d block

  int4v va, vb;
  auto stage_k = [&](int kv0, int bi) {
#pragma unroll
    for (int i = 0; i < 2; i++) {
      int unit = t + i * 256;
      int row = unit >> 3, sl = unit & 7;
      const unsigned short* g = Kp + (size_t)(kv0 + row) * 3072 + (sl ^ (row & 7)) * 8;
      __builtin_amdgcn_global_load_lds(to_glb(g), to_lds(&sK[bi][unit * 8]), 16, 0, 0);
    }
  };
  auto vload = [&](int kv0) {
    const unsigned short* g = Vp + (size_t)(kv0 + vkp * 2) * 3072 + vd0;
    va = *reinterpret_cast<const int4v*>(g);
    vb = *reinterpret_cast<const int4v*>(g + 3072);
  };
  auto vstore = [&](int bi) {
    const unsigned short* pa = (const unsigned short*)&va;
    const unsigned short* pb = (const unsigned short*)&vb;
#pragma unroll
    for (int j = 0; j < 8; j++) {
      int d = vd0 + j;
      unsigned int pk = (unsigned int)pa[j] | ((unsigned int)pb[j] << 16);
      int off = ((d * 64 + vkp * 2) * 2) ^ (((d >> 3) & 7) << 4);
      *(unsigned int*)((char*)sVT[bi] + off) = pk;
    }
  };

  const int nt = qt * 2 + 2;
  stage_k(0, 0);
  vload(0);
  vstore(0);
  __syncthreads();

  for (int ti = 0; ti < nt; ti++) {
    const int cur = ti & 1;
    const int kv0 = ti * 64;
    const bool last = (ti + 1 == nt);
    if (!last) { stage_k(kv0 + 64, cur ^ 1); vload(kv0 + 64); }

    if (kv0 <= q_end) {
      const char* Kb = (const char*)sK[cur];
      const char* Vb = (const char*)sVT[cur];
      char* Pb = (char*)sP[wave];

      // S^T = K · Q^T : st[m][c] rows = kv (c*16 + l4*4 + r), cols = q (l15)
      float4v st[2][4];
#pragma unroll
      for (int m = 0; m < 2; m++)
#pragma unroll
        for (int c = 0; c < 4; c++) st[m][c] = zero4();
#pragma unroll
      for (int kc = 0; kc < 2; kc++) {
#pragma unroll
        for (int c = 0; c < 4; c++) {
          int off = ((c * 16 + l15) * 128 + kc * 64 + l4 * 16) ^ ((l15 & 7) << 4);
          short8 ka = *reinterpret_cast<const short8*>(Kb + off);
          st[0][c] = __builtin_amdgcn_mfma_f32_16x16x32_bf16(ka, qf[0][kc], st[0][c], 0, 0, 0);
          st[1][c] = __builtin_amdgcn_mfma_f32_16x16x32_bf16(ka, qf[1][kc], st[1][c], 0, 0, 0);
        }
      }

#pragma unroll
      for (int m = 0; m < 2; m++) {
        const int qrow = q0w + m * 16 + l15;  // this lane's q column
        const bool needmask = (kv0 + 63 > q0w + m * 16);
        float pm = -1e30f;
#pragma unroll
        for (int c = 0; c < 4; c++)
#pragma unroll
          for (int r = 0; r < 4; r++) {
            float v = st[m][c][r] * scl;
            if (needmask) {
              int kv = kv0 + c * 16 + l4 * 4 + r;
              v = (kv <= qrow) ? v : -1e30f;
            }
            st[m][c][r] = v;
            pm = fmaxf(pm, v);
          }
        pm = fmaxf(pm, __shfl_xor(pm, 16, 64));
        pm = fmaxf(pm, __shfl_xor(pm, 32, 64));
        float mold = m_r[m];
        float ps = 0.f;
        if (__all(pm <= mold)) {  // defer-rescale fast path
#pragma unroll
          for (int c = 0; c < 4; c++)
#pragma unroll
            for (int r = 0; r < 4; r++) {
              float p = ex2(st[m][c][r] - mold);
              st[m][c][r] = p;
              ps += p;
            }
          ps += __shfl_xor(ps, 16, 64);
          ps += __shfl_xor(ps, 32, 64);
          l_r[m] += ps;
        } else {
          float newm = fmaxf(mold, pm);
          float sc = ex2(mold - newm);
          m_r[m] = newm;
#pragma unroll
          for (int c = 0; c < 4; c++)
#pragma unroll
            for (int r = 0; r < 4; r++) {
              float p = ex2(st[m][c][r] - newm);
              st[m][c][r] = p;
              ps += p;
            }
          ps += __shfl_xor(ps, 16, 64);
          ps += __shfl_xor(ps, 32, 64);
          l_r[m] = l_r[m] * sc + ps;
          float scr[4];
#pragma unroll
          for (int r = 0; r < 4; r++) scr[r] = __shfl(sc, l4 * 4 + r, 64);
#pragma unroll
          for (int f = 0; f < 4; f++)
#pragma unroll
            for (int r = 0; r < 4; r++) o_acc[m][f][r] *= scr[r];
        }
        // P -> LDS: packed b64, row q = m*16 + l15, cols kv = c*16 + l4*4 ..+4
#pragma unroll
        for (int c = 0; c < 4; c++) {
          unsigned long long w =
              (unsigned long long)cvtpk(st[m][c][0], st[m][c][1]) |
              ((unsigned long long)cvtpk(st[m][c][2], st[m][c][3]) << 32);
          int off = ((m * 16 + l15) * 128 + (c * 16 + l4 * 4) * 2) ^ ((l15 & 7) << 4);
          *(unsigned long long*)(Pb + off) = w;
        }
      }
      asm volatile("s_waitcnt lgkmcnt(0)" ::: "memory");
      __builtin_amdgcn_sched_barrier(0);

      // PV: O[q][d] += P[q][k] * V^T[d][k]
#pragma unroll
      for (int kc = 0; kc < 2; kc++) {
        short8 pa[2];
#pragma unroll
        for (int m = 0; m < 2; m++) {
          int off = ((m * 16 + l15) * 128 + kc * 64 + l4 * 16) ^ ((l15 & 7) << 4);
          pa[m] = *reinterpret_cast<const short8*>(Pb + off);
        }
#pragma unroll
        for (int f = 0; f < 4; f++) {
          int d = f * 16 + l15;
          int off = (d * 128 + kc * 64 + l4 * 16) ^ (((d >> 3) & 7) << 4);
          short8 vbf = *reinterpret_cast<const short8*>(Vb + off);
          o_acc[0][f] = __builtin_amdgcn_mfma_f32_16x16x32_bf16(pa[0], vbf, o_acc[0][f], 0, 0, 0);
          o_acc[1][f] = __builtin_amdgcn_mfma_f32_16x16x32_bf16(pa[1], vbf, o_acc[1][f], 0, 0, 0);
        }
      }
    }
    if (!last) vstore(cur ^ 1);
    __syncthreads();
  }

  unsigned short* yb = y + (size_t)b * T * 1024 + h * 64;
#pragma unroll
  for (int m = 0; m < 2; m++) {
    float lr[4];
#pragma unroll
    for (int r = 0; r < 4; r++) lr[r] = 1.0f / __shfl(l_r[m], l4 * 4 + r, 64);
#pragma unroll
    for (int f = 0; f < 4; f++)
#pragma unroll
      for (int r = 0; r < 4; r++) {
        int q = q0w + m * 16 + l4 * 4 + r;
        yb[(size_t)q * 1024 + f * 16 + l15] = f2bf(o_acc[m][f][r] * lr[r]);
      }
  }
}

// ---------------------------------------------------------------- launch
extern "C" void kernel_launch(void* const* d_in, const int* in_sizes, int n_in,
                              void* d_out, int out_size, void* d_ws, size_t ws_size,
                              hipStream_t stream) {
  const float* x = (const float*)d_in[0];
  const float* w_qkv = (const float*)d_in[1];
  const float* b_qkv = (const float*)d_in[2];
  const float* w_proj = (const float*)d_in[3];
  const float* b_proj = (const float*)d_in[4];
  float* out = (float*)d_out;
  char* ws = (char*)d_ws;

  const int M = 4 * 2048;
  unsigned short* x_bf = (unsigned short*)ws;
  unsigned short* wqkv_bf = (unsigned short*)(ws + (22ull << 20));
  unsigned short* wproj_bf = (unsigned short*)(ws + (28ull << 20));
  unsigned short* qkv = (unsigned short*)(ws + (30ull << 20));
  unsigned short* y_bf = x_bf;  // reuse x region after QKV GEMM

  f32_to_bf16_kn<<<2048, 256, 0, stream>>>(x, x_bf, M * 1024);
  f32_to_bf16_kn<<<1024, 256, 0, stream>>>(w_qkv, wqkv_bf, 3072 * 1024);
  f32_to_bf16_kn<<<512, 256, 0, stream>>>(w_proj, wproj_bf, 1024 * 1024);

  gemm_bt_kn<0><<<dim3(3072 / 128, M / 128), 256, 0, stream>>>(x_bf, wqkv_bf, b_qkv, qkv, M, 3072, 1024);

  attn_kn<<<dim3(2048 / 64 / 2 * 1, 64), 256, 0, stream>>>(qkv, y_bf);  // 16 q-tiles of 128

  gemm_bt_kn<1><<<dim3(1024 / 128, M / 128), 256, 0, stream>>>(y_bf, wproj_bf, b_proj, out, M, 1024, 1024);
}

// Round 3
// 180.759 us; speedup vs baseline: 3.3665x; 1.3949x over previous
//
#include <hip/hip_runtime.h>
#include <hip/hip_bf16.h>

#define DEV static __device__ __forceinline__

typedef __attribute__((ext_vector_type(8))) short short8;
typedef __attribute__((ext_vector_type(4))) short short4v;
typedef __attribute__((ext_vector_type(4))) float float4v;
typedef __attribute__((ext_vector_type(4))) int int4v;

DEV unsigned short f2bf(float f) {
  unsigned int u = __builtin_bit_cast(unsigned int, f);
  u = (u + 0x7fffu + ((u >> 16) & 1u)) >> 16;
  return (unsigned short)u;
}

DEV __attribute__((address_space(3))) void* to_lds(void* p) {
  return (__attribute__((address_space(3))) void*)p;
}
DEV const __attribute__((address_space(1))) void* to_glb(const void* p) {
  return (const __attribute__((address_space(1))) void*)p;
}

DEV float4v zero4() { float4v z = {0.f, 0.f, 0.f, 0.f}; return z; }

DEV float ex2(float x) {
  float r;
  asm("v_exp_f32 %0, %1" : "=v"(r) : "v"(x));
  return r;
}
DEV unsigned int cvtpk(float lo, float hi) {
  unsigned int r;
  asm("v_cvt_pk_bf16_f32 %0, %1, %2" : "=v"(r) : "v"(lo), "v"(hi));
  return r;
}

// ---------------------------------------------------------------- convert
__global__ __launch_bounds__(256)
void f32_to_bf16_kn(const float* __restrict__ src, unsigned short* __restrict__ dst, int n) {
  int i = (blockIdx.x * blockDim.x + threadIdx.x) * 4;
  int stride = gridDim.x * blockDim.x * 4;
  for (; i < n; i += stride) {
    float4v v = *reinterpret_cast<const float4v*>(src + i);
    short4v o;
    o[0] = (short)f2bf(v[0]);
    o[1] = (short)f2bf(v[1]);
    o[2] = (short)f2bf(v[2]);
    o[3] = (short)f2bf(v[3]);
    *reinterpret_cast<short4v*>(dst + i) = o;
  }
}

// ---------------------------------------------------------------- GEMM (B^T form)
template<int OUT_F32>
__global__ __launch_bounds__(256, 2)
void gemm_bt_kn(const unsigned short* __restrict__ A, const unsigned short* __restrict__ B,
                const float* __restrict__ bias, void* __restrict__ Cout,
                int M, int N, int K) {
  __shared__ unsigned short sA[128 * 64];
  __shared__ unsigned short sB[128 * 64];
  const int t = threadIdx.x;
  const int wave = t >> 6, lane = t & 63;
  const int wm = wave >> 1, wn = wave & 1;
  const int m0 = blockIdx.y * 128, n0 = blockIdx.x * 128;
  const int l15 = lane & 15, l4 = lane >> 4;

  float4v acc[4][4];
#pragma unroll
  for (int i = 0; i < 4; i++)
#pragma unroll
    for (int j = 0; j < 4; j++) acc[i][j] = zero4();

  const int row_s = t >> 3;
  const int cols_s = ((t & 7) ^ ((t >> 3) & 7)) * 8;

  for (int k0 = 0; k0 < K; k0 += 64) {
    __syncthreads();
#pragma unroll
    for (int i = 0; i < 4; i++) {
      const unsigned short* ga = &A[(size_t)(m0 + row_s + i * 32) * K + k0 + cols_s];
      __builtin_amdgcn_global_load_lds(to_glb(ga), to_lds(&sA[(i * 4096 + wave * 1024) / 2]), 16, 0, 0);
    }
#pragma unroll
    for (int i = 0; i < 4; i++) {
      const unsigned short* gb = &B[(size_t)(n0 + row_s + i * 32) * K + k0 + cols_s];
      __builtin_amdgcn_global_load_lds(to_glb(gb), to_lds(&sB[(i * 4096 + wave * 1024) / 2]), 16, 0, 0);
    }
    __syncthreads();
#pragma unroll
    for (int kc = 0; kc < 2; kc++) {
      short8 af[4], bf[4];
#pragma unroll
      for (int mf = 0; mf < 4; mf++) {
        int off = ((wm * 64 + mf * 16 + l15) * 128 + kc * 64 + l4 * 16) ^ ((l15 & 7) << 4);
        af[mf] = *reinterpret_cast<const short8*>((const char*)sA + off);
      }
#pragma unroll
      for (int nf = 0; nf < 4; nf++) {
        int off = ((wn * 64 + nf * 16 + l15) * 128 + kc * 64 + l4 * 16) ^ ((l15 & 7) << 4);
        bf[nf] = *reinterpret_cast<const short8*>((const char*)sB + off);
      }
      __builtin_amdgcn_s_setprio(1);
#pragma unroll
      for (int mf = 0; mf < 4; mf++)
#pragma unroll
        for (int nf = 0; nf < 4; nf++)
          acc[mf][nf] = __builtin_amdgcn_mfma_f32_16x16x32_bf16(af[mf], bf[nf], acc[mf][nf], 0, 0, 0);
      __builtin_amdgcn_s_setprio(0);
    }
  }

#pragma unroll
  for (int mf = 0; mf < 4; mf++) {
#pragma unroll
    for (int nf = 0; nf < 4; nf++) {
#pragma unroll
      for (int r = 0; r < 4; r++) {
        int row = m0 + wm * 64 + mf * 16 + l4 * 4 + r;
        int col = n0 + wn * 64 + nf * 16 + l15;
        float v = acc[mf][nf][r] + bias[col];
        if (OUT_F32)
          ((float*)Cout)[(size_t)row * N + col] = v;
        else
          ((unsigned short*)Cout)[(size_t)row * N + col] = f2bf(v);
      }
    }
  }
}

// ---------------------------------------------------------------- attention
// Balanced: each block handles q-tile pair (p, 15-p) => exactly 34 kv-tiles.
// grid (64 bh, 8 pair) so all pair-blocks of one head share an XCD (id%8=bh%8).
// Swapped QK^T, KVBLK=64, 4 waves x 32 q. Unified V^T swizzle key (d^(d>>3))&7.
__global__ __launch_bounds__(256, 2)
void attn_kn(const unsigned short* __restrict__ qkv, unsigned short* __restrict__ y) {
  __shared__ unsigned short sK[2][4096];   // [64 kv][64 d], key (row&7)<<4
  __shared__ unsigned short sVT[2][4096];  // [64 d][64 kv], key ((d^(d>>3))&7)<<4
  __shared__ unsigned short sP[4][2048];   // per-wave [32 q][64 kv], key (q&7)<<4
  const int t = threadIdx.x;
  const int wave = t >> 6, lane = t & 63;
  const int l15 = lane & 15, l4 = lane >> 4;
  const int bh = blockIdx.x;
  const int pairp = blockIdx.y;
  const int b = bh >> 4, h = bh & 15;
  const int T = 2048;
  const size_t base = (size_t)b * T * 3072;
  const unsigned short* Qp = qkv + base + h * 64;
  const unsigned short* Kp = qkv + base + 1024 + h * 64;
  const unsigned short* Vp = qkv + base + 2048 + h * 64;
  const float scl = 0.125f * 1.44269504089f;  // 1/sqrt(64) * log2(e)

  const int vkp = t >> 3;       // kv-pair 0..31
  const int vd0 = (t & 7) * 8;  // d block

  int4v va, vb;
  auto stage_k = [&](int kv0, int bi) {
#pragma unroll
    for (int i = 0; i < 2; i++) {
      int unit = t + i * 256;
      int row = unit >> 3, sl = unit & 7;
      const unsigned short* g = Kp + (size_t)(kv0 + row) * 3072 + (sl ^ (row & 7)) * 8;
      __builtin_amdgcn_global_load_lds(to_glb(g), to_lds(&sK[bi][unit * 8]), 16, 0, 0);
    }
  };
  auto vload = [&](int kv0) {
    const unsigned short* g = Vp + (size_t)(kv0 + vkp * 2) * 3072 + vd0;
    va = *reinterpret_cast<const int4v*>(g);
    vb = *reinterpret_cast<const int4v*>(g + 3072);
  };
  auto vstore = [&](int bi) {
    const unsigned short* pa = (const unsigned short*)&va;
    const unsigned short* pb = (const unsigned short*)&vb;
#pragma unroll
    for (int j = 0; j < 8; j++) {
      int d = vd0 + j;
      unsigned int pk = (unsigned int)pa[j] | ((unsigned int)pb[j] << 16);
      int off = (d * 128 + vkp * 4) ^ (((d ^ (d >> 3)) & 7) << 4);
      *(unsigned int*)((char*)sVT[bi] + off) = pk;
    }
  };

  for (int ph = 0; ph < 2; ph++) {
    const int qt = ph ? (15 - pairp) : pairp;
    const int q0w = qt * 128 + wave * 32;
    const int q_end = q0w + 31;

    short8 qf[2][2];
#pragma unroll
    for (int m = 0; m < 2; m++)
#pragma unroll
      for (int kc = 0; kc < 2; kc++)
        qf[m][kc] = *reinterpret_cast<const short8*>(
            &Qp[(size_t)(q0w + m * 16 + l15) * 3072 + kc * 32 + l4 * 8]);

    float4v o_acc[2][4];
#pragma unroll
    for (int m = 0; m < 2; m++)
#pragma unroll
      for (int f = 0; f < 4; f++) o_acc[m][f] = zero4();
    float m_r[2] = {-1e30f, -1e30f};
    float l_r[2] = {0.f, 0.f};

    const int nt = qt * 2 + 2;
    stage_k(0, 0);
    vload(0);
    vstore(0);
    __syncthreads();

    for (int ti = 0; ti < nt; ti++) {
      const int cur = ti & 1;
      const int kv0 = ti * 64;
      const bool last = (ti + 1 == nt);
      if (!last) { stage_k(kv0 + 64, cur ^ 1); vload(kv0 + 64); }

      if (kv0 <= q_end) {
        const char* Kb = (const char*)sK[cur];
        const char* Vb = (const char*)sVT[cur];
        char* Pb = (char*)sP[wave];

        // S^T = K · Q^T : rows kv (c*16 + l4*4 + r), cols q (l15)
        float4v st[2][4];
#pragma unroll
        for (int m = 0; m < 2; m++)
#pragma unroll
          for (int c = 0; c < 4; c++) st[m][c] = zero4();
#pragma unroll
        for (int kc = 0; kc < 2; kc++) {
          short8 ka[4];
#pragma unroll
          for (int c = 0; c < 4; c++) {
            int off = ((c * 16 + l15) * 128 + kc * 64 + l4 * 16) ^ ((l15 & 7) << 4);
            ka[c] = *reinterpret_cast<const short8*>(Kb + off);
          }
          __builtin_amdgcn_s_setprio(1);
#pragma unroll
          for (int c = 0; c < 4; c++) {
            st[0][c] = __builtin_amdgcn_mfma_f32_16x16x32_bf16(ka[c], qf[0][kc], st[0][c], 0, 0, 0);
            st[1][c] = __builtin_amdgcn_mfma_f32_16x16x32_bf16(ka[c], qf[1][kc], st[1][c], 0, 0, 0);
          }
          __builtin_amdgcn_s_setprio(0);
        }

#pragma unroll
        for (int m = 0; m < 2; m++) {
          const int qrow = q0w + m * 16 + l15;  // this lane's q column
          const bool needmask = (kv0 + 63 > q0w + m * 16);
          if (needmask) {
#pragma unroll
            for (int c = 0; c < 4; c++)
#pragma unroll
              for (int r = 0; r < 4; r++) {
                int kv = kv0 + c * 16 + l4 * 4 + r;
                if (kv > qrow) st[m][c][r] = -1e30f;
              }
          }
          float pm = -1e30f;
#pragma unroll
          for (int c = 0; c < 4; c++)
#pragma unroll
            for (int r = 0; r < 4; r++) pm = fmaxf(pm, st[m][c][r]);
          pm = fmaxf(pm, __shfl_xor(pm, 16, 64));
          pm = fmaxf(pm, __shfl_xor(pm, 32, 64));

          float mold = m_r[m];
          float mm = mold;
          if (!__all(pm <= mold + 44.0f)) {  // THR=8 in log2 units (8/scl)
            mm = fmaxf(mold, pm);
            float sc = ex2((mold - mm) * scl);
            m_r[m] = mm;
            l_r[m] *= sc;
            float scr[4];
#pragma unroll
            for (int r = 0; r < 4; r++) scr[r] = __shfl(sc, l4 * 4 + r, 64);
#pragma unroll
            for (int f = 0; f < 4; f++)
#pragma unroll
              for (int r = 0; r < 4; r++) o_acc[m][f][r] *= scr[r];
          }
          const float mscl = mm * scl;
          float ps = 0.f;
#pragma unroll
          for (int c = 0; c < 4; c++)
#pragma unroll
            for (int r = 0; r < 4; r++) {
              float p = ex2(fmaf(st[m][c][r], scl, -mscl));
              st[m][c][r] = p;
              ps += p;
            }
          ps += __shfl_xor(ps, 16, 64);
          ps += __shfl_xor(ps, 32, 64);
          l_r[m] += ps;

#pragma unroll
          for (int c = 0; c < 4; c++) {
            unsigned long long w =
                (unsigned long long)cvtpk(st[m][c][0], st[m][c][1]) |
                ((unsigned long long)cvtpk(st[m][c][2], st[m][c][3]) << 32);
            int off = ((m * 16 + l15) * 128 + (c * 16 + l4 * 4) * 2) ^ ((l15 & 7) << 4);
            *(unsigned long long*)(Pb + off) = w;
          }
        }
        asm volatile("s_waitcnt lgkmcnt(0)" ::: "memory");
        __builtin_amdgcn_sched_barrier(0);

        // PV: O[q][d] += P[q][k] * V^T[d][k]
#pragma unroll
        for (int kc = 0; kc < 2; kc++) {
          short8 pa[2];
#pragma unroll
          for (int m = 0; m < 2; m++) {
            int off = ((m * 16 + l15) * 128 + kc * 64 + l4 * 16) ^ ((l15 & 7) << 4);
            pa[m] = *reinterpret_cast<const short8*>(Pb + off);
          }
#pragma unroll
          for (int f = 0; f < 4; f++) {
            int d = f * 16 + l15;
            int off = (d * 128 + kc * 64 + l4 * 16) ^ (((d ^ (d >> 3)) & 7) << 4);
            short8 vbf = *reinterpret_cast<const short8*>(Vb + off);
            __builtin_amdgcn_s_setprio(1);
            o_acc[0][f] = __builtin_amdgcn_mfma_f32_16x16x32_bf16(pa[0], vbf, o_acc[0][f], 0, 0, 0);
            o_acc[1][f] = __builtin_amdgcn_mfma_f32_16x16x32_bf16(pa[1], vbf, o_acc[1][f], 0, 0, 0);
            __builtin_amdgcn_s_setprio(0);
          }
        }
      }
      if (!last) vstore(cur ^ 1);
      __syncthreads();
    }

    unsigned short* yb = y + (size_t)b * T * 1024 + h * 64;
#pragma unroll
    for (int m = 0; m < 2; m++) {
      float lr[4];
#pragma unroll
      for (int r = 0; r < 4; r++) lr[r] = 1.0f / __shfl(l_r[m], l4 * 4 + r, 64);
#pragma unroll
      for (int f = 0; f < 4; f++)
#pragma unroll
        for (int r = 0; r < 4; r++) {
          int q = q0w + m * 16 + l4 * 4 + r;
          yb[(size_t)q * 1024 + f * 16 + l15] = f2bf(o_acc[m][f][r] * lr[r]);
        }
    }
  }
}

// ---------------------------------------------------------------- launch
extern "C" void kernel_launch(void* const* d_in, const int* in_sizes, int n_in,
                              void* d_out, int out_size, void* d_ws, size_t ws_size,
                              hipStream_t stream) {
  const float* x = (const float*)d_in[0];
  const float* w_qkv = (const float*)d_in[1];
  const float* b_qkv = (const float*)d_in[2];
  const float* w_proj = (const float*)d_in[3];
  const float* b_proj = (const float*)d_in[4];
  float* out = (float*)d_out;
  char* ws = (char*)d_ws;

  const int M = 4 * 2048;
  unsigned short* x_bf = (unsigned short*)ws;
  unsigned short* wqkv_bf = (unsigned short*)(ws + (22ull << 20));
  unsigned short* wproj_bf = (unsigned short*)(ws + (28ull << 20));
  unsigned short* qkv = (unsigned short*)(ws + (30ull << 20));
  unsigned short* y_bf = x_bf;  // reuse x region after QKV GEMM

  f32_to_bf16_kn<<<2048, 256, 0, stream>>>(x, x_bf, M * 1024);
  f32_to_bf16_kn<<<1024, 256, 0, stream>>>(w_qkv, wqkv_bf, 3072 * 1024);
  f32_to_bf16_kn<<<512, 256, 0, stream>>>(w_proj, wproj_bf, 1024 * 1024);

  gemm_bt_kn<0><<<dim3(3072 / 128, M / 128), 256, 0, stream>>>(x_bf, wqkv_bf, b_qkv, qkv, M, 3072, 1024);

  attn_kn<<<dim3(64, 8), 256, 0, stream>>>(qkv, y_bf);

  gemm_bt_kn<1><<<dim3(1024 / 128, M / 128), 256, 0, stream>>>(y_bf, wproj_bf, b_proj, out, M, 1024, 1024);
}

// Round 4
// 172.960 us; speedup vs baseline: 3.5183x; 1.0451x over previous
//
#include <hip/hip_runtime.h>
#include <hip/hip_bf16.h>

#define DEV static __device__ __forceinline__

typedef __attribute__((ext_vector_type(8))) short short8;
typedef __attribute__((ext_vector_type(4))) short short4v;
typedef __attribute__((ext_vector_type(4))) float float4v;
typedef __attribute__((ext_vector_type(4))) int int4v;

DEV unsigned short f2bf(float f) {
  unsigned int u = __builtin_bit_cast(unsigned int, f);
  u = (u + 0x7fffu + ((u >> 16) & 1u)) >> 16;
  return (unsigned short)u;
}

DEV __attribute__((address_space(3))) void* to_lds(void* p) {
  return (__attribute__((address_space(3))) void*)p;
}
DEV const __attribute__((address_space(1))) void* to_glb(const void* p) {
  return (const __attribute__((address_space(1))) void*)p;
}

DEV float4v zero4() { float4v z = {0.f, 0.f, 0.f, 0.f}; return z; }

DEV float ex2(float x) {
  float r;
  asm("v_exp_f32 %0, %1" : "=v"(r) : "v"(x));
  return r;
}
DEV unsigned int cvtpk(float lo, float hi) {
  unsigned int r;
  asm("v_cvt_pk_bf16_f32 %0, %1, %2" : "=v"(r) : "v"(lo), "v"(hi));
  return r;
}

// ---------------------------------------------------------------- convert
__global__ __launch_bounds__(256)
void f32_to_bf16_kn(const float* __restrict__ src, unsigned short* __restrict__ dst, int n) {
  int i = (blockIdx.x * blockDim.x + threadIdx.x) * 4;
  int stride = gridDim.x * blockDim.x * 4;
  for (; i < n; i += stride) {
    float4v v = *reinterpret_cast<const float4v*>(src + i);
    short4v o;
    o[0] = (short)f2bf(v[0]);
    o[1] = (short)f2bf(v[1]);
    o[2] = (short)f2bf(v[2]);
    o[3] = (short)f2bf(v[3]);
    *reinterpret_cast<short4v*>(dst + i) = o;
  }
}

// ---------------------------------------------------------------- GEMM (B^T form)
// SCALE_Q: multiply output cols < 1024 (the q block of qkv) by 0.125*log2e,
// so attention scores arrive in log2 units with the softmax scale folded in.
template<int OUT_F32, int SCALE_Q>
__global__ __launch_bounds__(256, 2)
void gemm_bt_kn(const unsigned short* __restrict__ A, const unsigned short* __restrict__ B,
                const float* __restrict__ bias, void* __restrict__ Cout,
                int M, int N, int K) {
  __shared__ unsigned short sA[128 * 64];
  __shared__ unsigned short sB[128 * 64];
  const int t = threadIdx.x;
  const int wave = t >> 6, lane = t & 63;
  const int wm = wave >> 1, wn = wave & 1;
  const int m0 = blockIdx.y * 128, n0 = blockIdx.x * 128;
  const int l15 = lane & 15, l4 = lane >> 4;

  float4v acc[4][4];
#pragma unroll
  for (int i = 0; i < 4; i++)
#pragma unroll
    for (int j = 0; j < 4; j++) acc[i][j] = zero4();

  const int row_s = t >> 3;
  const int cols_s = ((t & 7) ^ ((t >> 3) & 7)) * 8;

  for (int k0 = 0; k0 < K; k0 += 64) {
    __syncthreads();
#pragma unroll
    for (int i = 0; i < 4; i++) {
      const unsigned short* ga = &A[(size_t)(m0 + row_s + i * 32) * K + k0 + cols_s];
      __builtin_amdgcn_global_load_lds(to_glb(ga), to_lds(&sA[(i * 4096 + wave * 1024) / 2]), 16, 0, 0);
    }
#pragma unroll
    for (int i = 0; i < 4; i++) {
      const unsigned short* gb = &B[(size_t)(n0 + row_s + i * 32) * K + k0 + cols_s];
      __builtin_amdgcn_global_load_lds(to_glb(gb), to_lds(&sB[(i * 4096 + wave * 1024) / 2]), 16, 0, 0);
    }
    __syncthreads();
#pragma unroll
    for (int kc = 0; kc < 2; kc++) {
      short8 af[4], bf[4];
#pragma unroll
      for (int mf = 0; mf < 4; mf++) {
        int off = ((wm * 64 + mf * 16 + l15) * 128 + kc * 64 + l4 * 16) ^ ((l15 & 7) << 4);
        af[mf] = *reinterpret_cast<const short8*>((const char*)sA + off);
      }
#pragma unroll
      for (int nf = 0; nf < 4; nf++) {
        int off = ((wn * 64 + nf * 16 + l15) * 128 + kc * 64 + l4 * 16) ^ ((l15 & 7) << 4);
        bf[nf] = *reinterpret_cast<const short8*>((const char*)sB + off);
      }
      __builtin_amdgcn_s_setprio(1);
#pragma unroll
      for (int mf = 0; mf < 4; mf++)
#pragma unroll
        for (int nf = 0; nf < 4; nf++)
          acc[mf][nf] = __builtin_amdgcn_mfma_f32_16x16x32_bf16(af[mf], bf[nf], acc[mf][nf], 0, 0, 0);
      __builtin_amdgcn_s_setprio(0);
    }
  }

#pragma unroll
  for (int mf = 0; mf < 4; mf++) {
#pragma unroll
    for (int nf = 0; nf < 4; nf++) {
#pragma unroll
      for (int r = 0; r < 4; r++) {
        int row = m0 + wm * 64 + mf * 16 + l4 * 4 + r;
        int col = n0 + wn * 64 + nf * 16 + l15;
        float v = acc[mf][nf][r] + bias[col];
        if (SCALE_Q && col < 1024) v *= 0.18033688f;  // 0.125 * log2(e)
        if (OUT_F32)
          ((float*)Cout)[(size_t)row * N + col] = v;
        else
          ((unsigned short*)Cout)[(size_t)row * N + col] = f2bf(v);
      }
    }
  }
}

// ---------------------------------------------------------------- attention
// 64-q-row blocks (4 waves x 16 q), pair-balanced (p, 31-p) => 33 kv-tiles per
// block, grid 64 x 16 = 1024 blocks (4/CU). Swapped QK^T; scores in log2 units
// (Q pre-scaled in GEMM). Row-sum l computed by MFMA against a ones B-frag.
__global__ __launch_bounds__(256, 4)
void attn_kn(const unsigned short* __restrict__ qkv, unsigned short* __restrict__ y) {
  __shared__ unsigned short sK[2][4096];   // [64 kv][64 d], key (row&7)<<4
  __shared__ unsigned short sVT[2][4096];  // [64 d][64 kv], key ((d^(d>>3))&7)<<4
  __shared__ unsigned short sP[4][1024];   // per-wave [16 q][64 kv], key (q&7)<<4
  const int t = threadIdx.x;
  const int wave = t >> 6, lane = t & 63;
  const int l15 = lane & 15, l4 = lane >> 4;
  const int bh = blockIdx.x;
  const int pairp = blockIdx.y;
  const int b = bh >> 4, h = bh & 15;
  const int T = 2048;
  const size_t base = (size_t)b * T * 3072;
  const unsigned short* Qp = qkv + base + h * 64;
  const unsigned short* Kp = qkv + base + 1024 + h * 64;
  const unsigned short* Vp = qkv + base + 2048 + h * 64;

  short8 ones;
#pragma unroll
  for (int j = 0; j < 8; j++) ones[j] = (short)0x3F80;  // bf16 1.0

  const int vkp = t >> 3;
  const int vd0 = (t & 7) * 8;

  int4v va, vb;
  auto stage_k = [&](int kv0, int bi) {
#pragma unroll
    for (int i = 0; i < 2; i++) {
      int unit = t + i * 256;
      int row = unit >> 3, sl = unit & 7;
      const unsigned short* g = Kp + (size_t)(kv0 + row) * 3072 + (sl ^ (row & 7)) * 8;
      __builtin_amdgcn_global_load_lds(to_glb(g), to_lds(&sK[bi][unit * 8]), 16, 0, 0);
    }
  };
  auto vload = [&](int kv0) {
    const unsigned short* g = Vp + (size_t)(kv0 + vkp * 2) * 3072 + vd0;
    va = *reinterpret_cast<const int4v*>(g);
    vb = *reinterpret_cast<const int4v*>(g + 3072);
  };
  auto vstore = [&](int bi) {
    const unsigned short* pa = (const unsigned short*)&va;
    const unsigned short* pb = (const unsigned short*)&vb;
#pragma unroll
    for (int j = 0; j < 8; j++) {
      int d = vd0 + j;
      unsigned int pk = (unsigned int)pa[j] | ((unsigned int)pb[j] << 16);
      int off = (d * 128 + vkp * 4) ^ (((d ^ (d >> 3)) & 7) << 4);
      *(unsigned int*)((char*)sVT[bi] + off) = pk;
    }
  };

  for (int ph = 0; ph < 2; ph++) {
    const int qt = ph ? (31 - pairp) : pairp;  // q-tile of 64 rows
    const int q0w = qt * 64 + wave * 16;
    const int qrow = q0w + l15;  // this lane's q column in S^T

    short8 qf[2];
#pragma unroll
    for (int kc = 0; kc < 2; kc++)
      qf[kc] = *reinterpret_cast<const short8*>(
          &Qp[(size_t)(q0w + l15) * 3072 + kc * 32 + l4 * 8]);

    float4v o_acc[4];
#pragma unroll
    for (int f = 0; f < 4; f++) o_acc[f] = zero4();
    float4v acc_l = zero4();
    float m_r = -1e30f;

    const int nt = qt + 1;
    stage_k(0, 0);
    vload(0);
    vstore(0);
    __syncthreads();

    for (int ti = 0; ti < nt; ti++) {
      const int cur = ti & 1;
      const int kv0 = ti * 64;
      const bool last = (ti + 1 == nt);
      if (!last) { stage_k(kv0 + 64, cur ^ 1); vload(kv0 + 64); }

      const char* Kb = (const char*)sK[cur];
      const char* Vb = (const char*)sVT[cur];
      char* Pb = (char*)sP[wave];

      // S^T = K · Q^T : rows kv (c*16 + l4*4 + r), cols q (l15); log2 units
      float4v st[4];
#pragma unroll
      for (int c = 0; c < 4; c++) st[c] = zero4();
#pragma unroll
      for (int kc = 0; kc < 2; kc++) {
        short8 ka[4];
#pragma unroll
        for (int c = 0; c < 4; c++) {
          int off = ((c * 16 + l15) * 128 + kc * 64 + l4 * 16) ^ ((l15 & 7) << 4);
          ka[c] = *reinterpret_cast<const short8*>(Kb + off);
        }
        __builtin_amdgcn_s_setprio(1);
#pragma unroll
        for (int c = 0; c < 4; c++)
          st[c] = __builtin_amdgcn_mfma_f32_16x16x32_bf16(ka[c], qf[kc], st[c], 0, 0, 0);
        __builtin_amdgcn_s_setprio(0);
      }

      if (kv0 + 63 > q0w) {  // diagonal tile: causal mask
#pragma unroll
        for (int c = 0; c < 4; c++)
#pragma unroll
          for (int r = 0; r < 4; r++) {
            int kv = kv0 + c * 16 + l4 * 4 + r;
            if (kv > qrow) st[c][r] = -1e30f;
          }
      }
      float pm = -1e30f;
#pragma unroll
      for (int c = 0; c < 4; c++)
#pragma unroll
        for (int r = 0; r < 4; r++) pm = fmaxf(pm, st[c][r]);
      pm = fmaxf(pm, __shfl_xor(pm, 16, 64));
      pm = fmaxf(pm, __shfl_xor(pm, 32, 64));

      float mold = m_r;
      float mm = mold;
      if (!__all(pm <= mold + 11.5409f)) {  // defer-rescale: THR = 8 nats in log2
        mm = fmaxf(mold, pm);
        float sc = ex2(mold - mm);
        m_r = mm;
        float scr[4];
#pragma unroll
        for (int r = 0; r < 4; r++) scr[r] = __shfl(sc, l4 * 4 + r, 64);
#pragma unroll
        for (int r = 0; r < 4; r++) {
          acc_l[r] *= scr[r];
#pragma unroll
          for (int f = 0; f < 4; f++) o_acc[f][r] *= scr[r];
        }
      }
#pragma unroll
      for (int c = 0; c < 4; c++)
#pragma unroll
        for (int r = 0; r < 4; r++) st[c][r] = ex2(st[c][r] - mm);

#pragma unroll
      for (int c = 0; c < 4; c++) {
        unsigned long long w =
            (unsigned long long)cvtpk(st[c][0], st[c][1]) |
            ((unsigned long long)cvtpk(st[c][2], st[c][3]) << 32);
        int off = (l15 * 128 + (c * 16 + l4 * 4) * 2) ^ ((l15 & 7) << 4);
        *(unsigned long long*)(Pb + off) = w;
      }
      asm volatile("s_waitcnt lgkmcnt(0)" ::: "memory");
      __builtin_amdgcn_sched_barrier(0);

      // PV: O[q][d] += P[q][k] * V^T[d][k]; l[q] += P[q][k] * 1
#pragma unroll
      for (int kc = 0; kc < 2; kc++) {
        int poff = (l15 * 128 + kc * 64 + l4 * 16) ^ ((l15 & 7) << 4);
        short8 pa = *reinterpret_cast<const short8*>(Pb + poff);
        short8 vbf[4];
#pragma unroll
        for (int f = 0; f < 4; f++) {
          int d = f * 16 + l15;
          int off = (d * 128 + kc * 64 + l4 * 16) ^ (((d ^ (d >> 3)) & 7) << 4);
          vbf[f] = *reinterpret_cast<const short8*>(Vb + off);
        }
        __builtin_amdgcn_s_setprio(1);
#pragma unroll
        for (int f = 0; f < 4; f++)
          o_acc[f] = __builtin_amdgcn_mfma_f32_16x16x32_bf16(pa, vbf[f], o_acc[f], 0, 0, 0);
        acc_l = __builtin_amdgcn_mfma_f32_16x16x32_bf16(pa, ones, acc_l, 0, 0, 0);
        __builtin_amdgcn_s_setprio(0);
      }

      if (!last) vstore(cur ^ 1);
      __syncthreads();
    }

    unsigned short* yb = y + (size_t)b * T * 1024 + h * 64;
    float lr[4];
#pragma unroll
    for (int r = 0; r < 4; r++) lr[r] = 1.0f / acc_l[r];
#pragma unroll
    for (int f = 0; f < 4; f++)
#pragma unroll
      for (int r = 0; r < 4; r++) {
        int q = q0w + l4 * 4 + r;
        yb[(size_t)q * 1024 + f * 16 + l15] = f2bf(o_acc[f][r] * lr[r]);
      }
  }
}

// ---------------------------------------------------------------- launch
extern "C" void kernel_launch(void* const* d_in, const int* in_sizes, int n_in,
                              void* d_out, int out_size, void* d_ws, size_t ws_size,
                              hipStream_t stream) {
  const float* x = (const float*)d_in[0];
  const float* w_qkv = (const float*)d_in[1];
  const float* b_qkv = (const float*)d_in[2];
  const float* w_proj = (const float*)d_in[3];
  const float* b_proj = (const float*)d_in[4];
  float* out = (float*)d_out;
  char* ws = (char*)d_ws;

  const int M = 4 * 2048;
  unsigned short* x_bf = (unsigned short*)ws;
  unsigned short* wqkv_bf = (unsigned short*)(ws + (22ull << 20));
  unsigned short* wproj_bf = (unsigned short*)(ws + (28ull << 20));
  unsigned short* qkv = (unsigned short*)(ws + (30ull << 20));
  unsigned short* y_bf = x_bf;  // reuse x region after QKV GEMM

  f32_to_bf16_kn<<<2048, 256, 0, stream>>>(x, x_bf, M * 1024);
  f32_to_bf16_kn<<<1024, 256, 0, stream>>>(w_qkv, wqkv_bf, 3072 * 1024);
  f32_to_bf16_kn<<<512, 256, 0, stream>>>(w_proj, wproj_bf, 1024 * 1024);

  gemm_bt_kn<0, 1><<<dim3(3072 / 128, M / 128), 256, 0, stream>>>(x_bf, wqkv_bf, b_qkv, qkv, M, 3072, 1024);

  attn_kn<<<dim3(64, 16), 256, 0, stream>>>(qkv, y_bf);

  gemm_bt_kn<1, 0><<<dim3(1024 / 128, M / 128), 256, 0, stream>>>(y_bf, wproj_bf, b_proj, out, M, 1024, 1024);
}